// Round 4
// baseline (1872.806 us; speedup 1.0000x reference)
//
#include <hip/hip_runtime.h>
#include <stdint.h>

typedef unsigned short u16;
typedef __attribute__((ext_vector_type(8))) short bfrag;   // 8 bf16 = 4 VGPR
typedef __attribute__((ext_vector_type(4))) float f32x4;   // MFMA C/D

__device__ __forceinline__ uint32_t pack2bf(float x, float y) {
  uint32_t bx = __float_as_uint(x), by = __float_as_uint(y);
  bx += 0x7fffu + ((bx >> 16) & 1u);
  by += 0x7fffu + ((by >> 16) & 1u);
  return (bx >> 16) | (by & 0xffff0000u);
}
__device__ __forceinline__ u16 f2bf(float x) {
  uint32_t b = __float_as_uint(x);
  b += 0x7fffu + ((b >> 16) & 1u);
  return (u16)(b >> 16);
}
__device__ __forceinline__ float bflo(uint32_t p) { return __uint_as_float(p << 16); }
__device__ __forceinline__ float bfhi(uint32_t p) { return __uint_as_float(p & 0xffff0000u); }

// ---- x (f32) -> bf16 pairs ----
__global__ void k_cvt_x(const float* __restrict__ x, uint32_t* __restrict__ xb, int n4) {
  int i = blockIdx.x * blockDim.x + threadIdx.x;
  if (i >= n4) return;
  float4 v = ((const float4*)x)[i];
  xb[2 * i]     = pack2bf(v.x, v.y);
  xb[2 * i + 1] = pack2bf(v.z, v.w);
}

// ---- W[l][k][c] (f32) -> Wt[l][br][c][k] (bf16) ----
__global__ void k_cvt_w(const float* __restrict__ wp, const float* __restrict__ wn,
                        u16* __restrict__ wt, int total) {
  int i = blockIdx.x * blockDim.x + threadIdx.x;
  if (i >= total) return;
  int l = i >> 15;
  int rem = i & 32767;
  int br = rem >> 14;
  int rem2 = rem & 16383;
  int c = rem2 >> 7;
  int k = rem2 & 127;
  const float* w = br ? wn : wp;
  wt[i] = f2bf(w[l * 16384 + k * 128 + c]);
}

// ---- per-branch in-degree counts (dst) ----
__global__ void k_count(const int* __restrict__ ei, const float* __restrict__ ew,
                        int* __restrict__ cp, int* __restrict__ cn, int E) {
  int e = blockIdx.x * blockDim.x + threadIdx.x;
  if (e >= E) return;
  float w = ew[e];
  if (w == 0.f) return;
  int d = ei[E + e];
  atomicAdd(w > 0.f ? &cp[d] : &cn[d], 1);
}

// ---- exclusive scan of (cp+cn) : 3-kernel hierarchical ----
__global__ void k_scan1(const int* __restrict__ cp, const int* __restrict__ cn,
                        int* __restrict__ offs, int* __restrict__ part, int n) {
  __shared__ int sh[1024];
  int t = threadIdx.x;
  int i = blockIdx.x * 1024 + t;
  int v = (i < n) ? (cp[i] + cn[i]) : 0;
  sh[t] = v;
  __syncthreads();
  for (int off = 1; off < 1024; off <<= 1) {
    int add = (t >= off) ? sh[t - off] : 0;
    __syncthreads();
    sh[t] += add;
    __syncthreads();
  }
  if (i < n) offs[i] = sh[t] - v;   // exclusive within block
  if (t == 1023) part[blockIdx.x] = sh[1023];
}
__global__ void k_scan2(int* __restrict__ part, int* __restrict__ offs, int nb, int n) {
  if (threadIdx.x == 0 && blockIdx.x == 0) {
    int run = 0;
    for (int b = 0; b < nb; ++b) { int t = part[b]; part[b] = run; run += t; }
    offs[n] = run;
  }
}
__global__ void k_scan3(int* __restrict__ offs, const int* __restrict__ part,
                        const int* __restrict__ cp, const int* __restrict__ cn,
                        int* __restrict__ cur, float* __restrict__ dp, float* __restrict__ dn,
                        int n) {
  int i = blockIdx.x * blockDim.x + threadIdx.x;
  if (i >= n) return;
  int o = offs[i] + part[i >> 10];
  offs[i] = o;
  cur[i] = o;
  dp[i] = rsqrtf(1.f + (float)cp[i]);
  dn[i] = rsqrtf(1.f + (float)cn[i]);
}

// ---- build dst-sorted edge records {src | sign<<31} ----
__global__ void k_build(const int* __restrict__ ei, const float* __restrict__ ew,
                        int* __restrict__ cur, uint32_t* __restrict__ rec, int E) {
  int e = blockIdx.x * blockDim.x + threadIdx.x;
  if (e >= E) return;
  float w = ew[e];
  if (w == 0.f) return;
  int s = ei[e], d = ei[E + e];
  int p = atomicAdd(&cur[d], 1);
  rec[p] = (uint32_t)s | (w > 0.f ? 0u : 0x80000000u);
}

// ---- aggregation: one wave per dst node, both branches in one pass ----
__global__ void k_agg(const uint32_t* __restrict__ hin, const int* __restrict__ offs,
                      const uint32_t* __restrict__ rec,
                      const float* __restrict__ dp, const float* __restrict__ dn,
                      uint32_t* __restrict__ up, uint32_t* __restrict__ un, int n) {
  int gid = blockIdx.x * blockDim.x + threadIdx.x;
  int nd = gid >> 6, lane = gid & 63;
  if (nd >= n) return;
  int beg = offs[nd], end = offs[nd + 1];
  float dpd = dp[nd], dnd = dn[nd];
  float ap0 = 0.f, ap1 = 0.f, an0 = 0.f, an1 = 0.f;
  for (int j = beg; j < end; ++j) {
    uint32_t r = rec[j];                 // wave-uniform
    int s = (int)(r & 0x7fffffffu);
    uint32_t pk = hin[s * 64 + lane];
    float v0 = bflo(pk), v1 = bfhi(pk);
    if (!(r >> 31)) {                    // wave-uniform branch
      float nm = dp[s] * dpd;
      ap0 = fmaf(nm, v0, ap0); ap1 = fmaf(nm, v1, ap1);
    } else {
      float nm = dn[s] * dnd;
      an0 = fmaf(nm, v0, an0); an1 = fmaf(nm, v1, an1);
    }
  }
  float sp = dpd * dpd, sn = dnd * dnd;  // 1/deg = (rsqrt(deg))^2
  uint32_t hk = hin[nd * 64 + lane];
  float h0 = bflo(hk), h1 = bfhi(hk);
  up[nd * 64 + lane] = pack2bf(fmaf(sp, h0, ap0), fmaf(sp, h1, ap1));
  un[nd * 64 + lane] = pack2bf(fmaf(sn, h0, an0), fmaf(sn, h1, an1));
}

// ---- fused dual GEMM + bias + relu-diff: h = relu(uP@Wp+bp) - relu(uN@Wn+bn) ----
__global__ __launch_bounds__(256, 2) void k_gemm(
    const short* __restrict__ up, const short* __restrict__ un,
    const u16* __restrict__ wt, const float* __restrict__ bp, const float* __restrict__ bn,
    u16* __restrict__ hout, int nrows) {
  __shared__ __align__(16) u16 wl[32768];  // 64 KB: Wt_pos | Wt_neg, XOR-swizzled
  int t = threadIdx.x;
  for (int i = t; i < 4096; i += 256) {    // 4096 x 16B chunks
    int ci = i & 2047;
    int col = ci >> 4, kc16 = ci & 15;
    int db = (i >> 11) * 32768 + ((col * 256 + kc16 * 16) ^ ((col & 7) << 4));
    *(uint4*)((char*)wl + db) = ((const uint4*)wt)[i];
  }
  __syncthreads();
  int wv = t >> 6, lane = t & 63;
  int l15 = lane & 15, l4 = lane >> 4;
  int rowbase = blockIdx.x * 64 + wv * 16;
  int arow = rowbase + l15;
  if (arow >= nrows) arow = nrows - 1;
  f32x4 accP[8], accN[8];
#pragma unroll
  for (int i = 0; i < 8; ++i) { accP[i] = (f32x4)(0.f); accN[i] = (f32x4)(0.f); }
#pragma unroll
  for (int kc = 0; kc < 4; ++kc) {
    int koff = kc * 32 + l4 * 8;
    bfrag aP = *(const bfrag*)(up + (size_t)arow * 128 + koff);
    bfrag aN = *(const bfrag*)(un + (size_t)arow * 128 + koff);
#pragma unroll
    for (int nt = 0; nt < 8; ++nt) {
      int col = nt * 16 + l15;
      int bb = (col * 256 + kc * 64 + l4 * 16) ^ ((col & 7) << 4);
      bfrag bP = *(const bfrag*)((const char*)wl + bb);
      bfrag bN = *(const bfrag*)((const char*)wl + 32768 + bb);
      accP[nt] = __builtin_amdgcn_mfma_f32_16x16x32_bf16(aP, bP, accP[nt], 0, 0, 0);
      accN[nt] = __builtin_amdgcn_mfma_f32_16x16x32_bf16(aN, bN, accN[nt], 0, 0, 0);
    }
  }
#pragma unroll
  for (int nt = 0; nt < 8; ++nt) {
    int col = nt * 16 + l15;
    float vbp = bp[col], vbn = bn[col];
#pragma unroll
    for (int r = 0; r < 4; ++r) {
      int row = rowbase + l4 * 4 + r;
      if (row < nrows) {
        float vp = accP[nt][r] + vbp; vp = vp > 0.f ? vp : 0.f;
        float vn = accN[nt][r] + vbn; vn = vn > 0.f ? vn : 0.f;
        hout[(size_t)row * 128 + col] = f2bf(vp - vn);
      }
    }
  }
}

// ---- mean pool: one wave per 8 consecutive nodes (batch sorted -> few flushes) ----
__global__ void k_pool(const uint32_t* __restrict__ h, const int* __restrict__ batch,
                       float* __restrict__ pooled, float* __restrict__ gcnt, int n) {
  int gid = blockIdx.x * blockDim.x + threadIdx.x;
  int w = gid >> 6, lane = gid & 63;
  int n0 = w * 8;
  if (n0 >= n) return;
  int curg = -1, c = 0;
  float a0 = 0.f, a1 = 0.f;
  for (int i = 0; i < 8; ++i) {
    int nd = n0 + i;
    if (nd >= n) break;
    int g = batch[nd];
    if (g != curg) {
      if (curg >= 0) {
        atomicAdd(&pooled[curg * 128 + 2 * lane], a0);
        atomicAdd(&pooled[curg * 128 + 2 * lane + 1], a1);
        if (lane == 0) atomicAdd(gcnt + curg, (float)c);
      }
      curg = g; a0 = a1 = 0.f; c = 0;
    }
    uint32_t pk = h[nd * 64 + lane];
    a0 += bflo(pk); a1 += bfhi(pk); ++c;
  }
  if (curg >= 0) {
    atomicAdd(&pooled[curg * 128 + 2 * lane], a0);
    atomicAdd(&pooled[curg * 128 + 2 * lane + 1], a1);
    if (lane == 0) atomicAdd(gcnt + curg, (float)c);
  }
}

// ---- LayerNorm over D=128, one wave per graph ----
__global__ void k_ln(const float* __restrict__ pooled, const float* __restrict__ gcnt,
                     const float* __restrict__ gamma, const float* __restrict__ beta,
                     float* __restrict__ out, int G) {
  int gid = blockIdx.x * blockDim.x + threadIdx.x;
  int g = gid >> 6, lane = gid & 63;
  if (g >= G) return;
  float2 s = ((const float2*)pooled)[g * 64 + lane];
  float cm = fmaxf(gcnt[g], 1.f);
  float v0 = s.x / cm, v1 = s.y / cm;
  float tsum = v0 + v1;
#pragma unroll
  for (int m = 1; m < 64; m <<= 1) tsum += __shfl_xor(tsum, m, 64);
  float mu = tsum * (1.f / 128.f);
  float d0 = v0 - mu, d1 = v1 - mu;
  float q = d0 * d0 + d1 * d1;
#pragma unroll
  for (int m = 1; m < 64; m <<= 1) q += __shfl_xor(q, m, 64);
  float inv = rsqrtf(q * (1.f / 128.f) + 1e-5f);
  int f = 2 * lane;
  out[g * 128 + f]     = d0 * inv * gamma[f]     + beta[f];
  out[g * 128 + f + 1] = d1 * inv * gamma[f + 1] + beta[f + 1];
}

extern "C" void kernel_launch(void* const* d_in, const int* in_sizes, int n_in,
                              void* d_out, int out_size, void* d_ws, size_t ws_size,
                              hipStream_t stream) {
  const float* x     = (const float*)d_in[0];
  const int* ei      = (const int*)d_in[1];   // harness converts int64 -> int32
  const float* ew    = (const float*)d_in[2];
  const int* bt      = (const int*)d_in[3];   // int32
  const float* Wp    = (const float*)d_in[4];
  const float* bp    = (const float*)d_in[5];
  const float* Wn    = (const float*)d_in[6];
  const float* bn    = (const float*)d_in[7];
  const float* gamma = (const float*)d_in[8];
  const float* beta  = (const float*)d_in[9];
  int N = in_sizes[0] / 128;
  int E = in_sizes[1] / 2;
  int L = in_sizes[4] / (128 * 128);
  int G = out_size / 128;

  char* w = (char*)d_ws;
  auto alloc = [&](size_t bytes) {
    char* p = w;
    w += (bytes + 255) & ~(size_t)255;
    return p;
  };
  uint32_t* X   = (uint32_t*)alloc((size_t)N * 128 * 2);  // h (bf16 pairs)
  uint32_t* U   = (uint32_t*)alloc((size_t)N * 128 * 2);  // pos-branch agg
  uint32_t* V   = (uint32_t*)alloc((size_t)N * 128 * 2);  // neg-branch agg
  u16* wt       = (u16*)alloc((size_t)L * 2 * 128 * 128 * 2);
  uint32_t* rec = (uint32_t*)alloc((size_t)E * 4);
  int* cp       = (int*)alloc((size_t)N * 4);
  int* cn       = (int*)alloc((size_t)N * 4);
  int* offs     = (int*)alloc((size_t)(N + 1) * 4);
  int* cur      = (int*)alloc((size_t)N * 4);
  int* part     = (int*)alloc(1024 * 4);
  float* dp     = (float*)alloc((size_t)N * 4);
  float* dn     = (float*)alloc((size_t)N * 4);
  float* pooled = (float*)alloc((size_t)G * 128 * 4);
  float* gcnt   = (float*)alloc((size_t)G * 4);

  hipMemsetAsync(cp, 0, (size_t)N * 4, stream);
  hipMemsetAsync(cn, 0, (size_t)N * 4, stream);
  hipMemsetAsync(pooled, 0, (size_t)G * 128 * 4, stream);
  hipMemsetAsync(gcnt, 0, (size_t)G * 4, stream);

  int n4 = N * 32;
  k_cvt_x<<<(n4 + 255) / 256, 256, 0, stream>>>(x, X, n4);
  int wtot = L * 2 * 128 * 128;
  k_cvt_w<<<(wtot + 255) / 256, 256, 0, stream>>>(Wp, Wn, wt, wtot);
  k_count<<<(E + 255) / 256, 256, 0, stream>>>(ei, ew, cp, cn, E);
  int NB = (N + 1023) / 1024;
  k_scan1<<<NB, 1024, 0, stream>>>(cp, cn, offs, part, N);
  k_scan2<<<1, 64, 0, stream>>>(part, offs, NB, N);
  k_scan3<<<(N + 255) / 256, 256, 0, stream>>>(offs, part, cp, cn, cur, dp, dn, N);
  k_build<<<(E + 255) / 256, 256, 0, stream>>>(ei, ew, cur, rec, E);

  for (int l = 0; l < L; ++l) {
    k_agg<<<(N * 64 + 255) / 256, 256, 0, stream>>>(X, offs, rec, dp, dn, U, V, N);
    k_gemm<<<(N + 63) / 64, 256, 0, stream>>>((const short*)U, (const short*)V,
                                              wt + (size_t)l * 32768, bp + (size_t)l * 128,
                                              bn + (size_t)l * 128, (u16*)X, N);
  }
  k_pool<<<(((N + 7) / 8) * 64 + 255) / 256, 256, 0, stream>>>(X, bt, pooled, gcnt, N);
  k_ln<<<(G * 64 + 255) / 256, 256, 0, stream>>>(pooled, gcnt, gamma, beta, (float*)d_out, G);
}

// Round 5
// 1017.578 us; speedup vs baseline: 1.8405x; 1.8405x over previous
//
#include <hip/hip_runtime.h>
#include <stdint.h>

typedef unsigned short u16;
typedef __attribute__((ext_vector_type(8))) short bfrag;   // 8 bf16 = 4 VGPR
typedef __attribute__((ext_vector_type(4))) float f32x4;   // MFMA C/D

__device__ __forceinline__ uint32_t pack2bf(float x, float y) {
  uint32_t bx = __float_as_uint(x), by = __float_as_uint(y);
  bx += 0x7fffu + ((bx >> 16) & 1u);
  by += 0x7fffu + ((by >> 16) & 1u);
  return (bx >> 16) | (by & 0xffff0000u);
}
__device__ __forceinline__ u16 f2bf(float x) {
  uint32_t b = __float_as_uint(x);
  b += 0x7fffu + ((b >> 16) & 1u);
  return (u16)(b >> 16);
}
__device__ __forceinline__ float bflo(uint32_t p) { return __uint_as_float(p << 16); }
__device__ __forceinline__ float bfhi(uint32_t p) { return __uint_as_float(p & 0xffff0000u); }

// ---- x (f32) -> bf16 pairs ----
__global__ void k_cvt_x(const float* __restrict__ x, uint32_t* __restrict__ xb, int n4) {
  int i = blockIdx.x * blockDim.x + threadIdx.x;
  if (i >= n4) return;
  float4 v = ((const float4*)x)[i];
  xb[2 * i]     = pack2bf(v.x, v.y);
  xb[2 * i + 1] = pack2bf(v.z, v.w);
}

// ---- W[l][k][c] (f32) -> Wt[l][br][c][k] (bf16) ----
__global__ void k_cvt_w(const float* __restrict__ wp, const float* __restrict__ wn,
                        u16* __restrict__ wt, int total) {
  int i = blockIdx.x * blockDim.x + threadIdx.x;
  if (i >= total) return;
  int l = i >> 15;
  int rem = i & 32767;
  int br = rem >> 14;
  int rem2 = rem & 16383;
  int c = rem2 >> 7;
  int k = rem2 & 127;
  const float* w = br ? wn : wp;
  wt[i] = f2bf(w[l * 16384 + k * 128 + c]);
}

// ---- per-branch in-degree counts (dst) ----
__global__ void k_count(const int* __restrict__ ei, const float* __restrict__ ew,
                        int* __restrict__ cp, int* __restrict__ cn, int E) {
  int e = blockIdx.x * blockDim.x + threadIdx.x;
  if (e >= E) return;
  float w = ew[e];
  if (w == 0.f) return;
  int d = ei[E + e];
  atomicAdd(w > 0.f ? &cp[d] : &cn[d], 1);
}

// ---- exclusive scan of (cp+cn) : 3-kernel hierarchical ----
__global__ void k_scan1(const int* __restrict__ cp, const int* __restrict__ cn,
                        int* __restrict__ offs, int* __restrict__ part, int n) {
  __shared__ int sh[1024];
  int t = threadIdx.x;
  int i = blockIdx.x * 1024 + t;
  int v = (i < n) ? (cp[i] + cn[i]) : 0;
  sh[t] = v;
  __syncthreads();
  for (int off = 1; off < 1024; off <<= 1) {
    int add = (t >= off) ? sh[t - off] : 0;
    __syncthreads();
    sh[t] += add;
    __syncthreads();
  }
  if (i < n) offs[i] = sh[t] - v;   // exclusive within block
  if (t == 1023) part[blockIdx.x] = sh[1023];
}
__global__ void k_scan2(int* __restrict__ part, int* __restrict__ offs, int nb, int n) {
  if (threadIdx.x == 0 && blockIdx.x == 0) {
    int run = 0;
    for (int b = 0; b < nb; ++b) { int t = part[b]; part[b] = run; run += t; }
    offs[n] = run;
  }
}
__global__ void k_scan3(int* __restrict__ offs, const int* __restrict__ part,
                        const int* __restrict__ cp, const int* __restrict__ cn,
                        int* __restrict__ cur, float* __restrict__ dp, float* __restrict__ dn,
                        int n) {
  int i = blockIdx.x * blockDim.x + threadIdx.x;
  if (i >= n) return;
  int o = offs[i] + part[i >> 10];
  offs[i] = o;
  cur[i] = o;
  dp[i] = rsqrtf(1.f + (float)cp[i]);
  dn[i] = rsqrtf(1.f + (float)cn[i]);
}

// ---- build dst-sorted edge records {src, signed norm} (8 B) ----
__global__ void k_build(const int* __restrict__ ei, const float* __restrict__ ew,
                        const float* __restrict__ dp, const float* __restrict__ dn,
                        int* __restrict__ cur, int2* __restrict__ rec2, int E) {
  int e = blockIdx.x * blockDim.x + threadIdx.x;
  if (e >= E) return;
  float w = ew[e];
  if (w == 0.f) return;
  int s = ei[e], d = ei[E + e];
  int p = atomicAdd(&cur[d], 1);
  float nm = (w > 0.f) ? (dp[s] * dp[d]) : -(dn[s] * dn[d]);
  rec2[p] = make_int2(s, __float_as_int(nm));
}

// ---- aggregation: one wave per dst node, unroll-8 batched gathers, branchless ----
__global__ void k_agg(const uint32_t* __restrict__ hin, const int* __restrict__ offs,
                      const int2* __restrict__ rec2,
                      const float* __restrict__ dp, const float* __restrict__ dn,
                      uint32_t* __restrict__ up, uint32_t* __restrict__ un, int n) {
  int gid = blockIdx.x * blockDim.x + threadIdx.x;
  int nd = gid >> 6, lane = gid & 63;
  if (nd >= n) return;
  int beg = offs[nd], end = offs[nd + 1];
  float ap0 = 0.f, ap1 = 0.f, an0 = 0.f, an1 = 0.f;
  int j = beg;
  for (; j + 8 <= end; j += 8) {
    int2 rr[8];
#pragma unroll
    for (int u = 0; u < 8; ++u) rr[u] = rec2[j + u];
    uint32_t pk[8];
#pragma unroll
    for (int u = 0; u < 8; ++u) pk[u] = hin[(size_t)rr[u].x * 64 + lane];
#pragma unroll
    for (int u = 0; u < 8; ++u) {
      float nm = __int_as_float(rr[u].y);
      float np = fmaxf(nm, 0.f), nn = fmaxf(-nm, 0.f);
      float v0 = bflo(pk[u]), v1 = bfhi(pk[u]);
      ap0 = fmaf(np, v0, ap0); ap1 = fmaf(np, v1, ap1);
      an0 = fmaf(nn, v0, an0); an1 = fmaf(nn, v1, an1);
    }
  }
  for (; j < end; ++j) {
    int2 rr = rec2[j];
    uint32_t pk = hin[(size_t)rr.x * 64 + lane];
    float nm = __int_as_float(rr.y);
    float np = fmaxf(nm, 0.f), nn = fmaxf(-nm, 0.f);
    float v0 = bflo(pk), v1 = bfhi(pk);
    ap0 = fmaf(np, v0, ap0); ap1 = fmaf(np, v1, ap1);
    an0 = fmaf(nn, v0, an0); an1 = fmaf(nn, v1, an1);
  }
  float dpd = dp[nd], dnd = dn[nd];
  float sp = dpd * dpd, sn = dnd * dnd;  // 1/deg = (rsqrt(deg))^2
  uint32_t hk = hin[nd * 64 + lane];
  float h0 = bflo(hk), h1 = bfhi(hk);
  up[nd * 64 + lane] = pack2bf(fmaf(sp, h0, ap0), fmaf(sp, h1, ap1));
  un[nd * 64 + lane] = pack2bf(fmaf(sn, h0, an0), fmaf(sn, h1, an1));
}

// ---- fused dual GEMM + bias + relu-diff, persistent blocks ----
// h = relu(uP@Wp+bp) - relu(uN@Wn+bn); 128-row chunks, 4 waves x 2 row-tiles
__global__ __launch_bounds__(256, 2) void k_gemm(
    const short* __restrict__ up, const short* __restrict__ un,
    const u16* __restrict__ wt, const float* __restrict__ bp, const float* __restrict__ bn,
    u16* __restrict__ hout, int nrows, int nchunks) {
  __shared__ __align__(16) u16 wl[32768];  // 64 KB: Wt_pos | Wt_neg, XOR-swizzled
  int t = threadIdx.x;
  for (int i = t; i < 4096; i += 256) {    // 4096 x 16B chunks
    int ci = i & 2047;
    int col = ci >> 4, kc16 = ci & 15;
    int db = (i >> 11) * 32768 + ((col * 256 + kc16 * 16) ^ ((col & 7) << 4));
    *(uint4*)((char*)wl + db) = ((const uint4*)wt)[i];
  }
  __syncthreads();
  int wv = t >> 6, lane = t & 63;
  int l15 = lane & 15, l4 = lane >> 4;
  float vbp[8], vbn[8];
#pragma unroll
  for (int nt = 0; nt < 8; ++nt) {
    vbp[nt] = bp[nt * 16 + l15];
    vbn[nt] = bn[nt * 16 + l15];
  }
  for (int c = blockIdx.x; c < nchunks; c += gridDim.x) {
    int rowbase = c * 128 + wv * 32;
    int r0 = rowbase + l15;      if (r0 >= nrows) r0 = nrows - 1;
    int r1 = rowbase + 16 + l15; if (r1 >= nrows) r1 = nrows - 1;
    f32x4 accP[2][8], accN[2][8];
#pragma unroll
    for (int rt = 0; rt < 2; ++rt)
#pragma unroll
      for (int nt = 0; nt < 8; ++nt) { accP[rt][nt] = (f32x4)(0.f); accN[rt][nt] = (f32x4)(0.f); }
#pragma unroll
    for (int kc = 0; kc < 4; ++kc) {
      int koff = kc * 32 + l4 * 8;
      bfrag aP0 = *(const bfrag*)(up + (size_t)r0 * 128 + koff);
      bfrag aP1 = *(const bfrag*)(up + (size_t)r1 * 128 + koff);
      bfrag aN0 = *(const bfrag*)(un + (size_t)r0 * 128 + koff);
      bfrag aN1 = *(const bfrag*)(un + (size_t)r1 * 128 + koff);
#pragma unroll
      for (int nt = 0; nt < 8; ++nt) {
        int col = nt * 16 + l15;
        int bb = (col * 256 + kc * 64 + l4 * 16) ^ ((col & 7) << 4);
        bfrag bP = *(const bfrag*)((const char*)wl + bb);
        bfrag bN = *(const bfrag*)((const char*)wl + 32768 + bb);
        accP[0][nt] = __builtin_amdgcn_mfma_f32_16x16x32_bf16(aP0, bP, accP[0][nt], 0, 0, 0);
        accP[1][nt] = __builtin_amdgcn_mfma_f32_16x16x32_bf16(aP1, bP, accP[1][nt], 0, 0, 0);
        accN[0][nt] = __builtin_amdgcn_mfma_f32_16x16x32_bf16(aN0, bN, accN[0][nt], 0, 0, 0);
        accN[1][nt] = __builtin_amdgcn_mfma_f32_16x16x32_bf16(aN1, bN, accN[1][nt], 0, 0, 0);
      }
    }
#pragma unroll
    for (int rt = 0; rt < 2; ++rt) {
#pragma unroll
      for (int nt = 0; nt < 8; ++nt) {
        int col = nt * 16 + l15;
#pragma unroll
        for (int r = 0; r < 4; ++r) {
          int row = rowbase + rt * 16 + l4 * 4 + r;
          if (row < nrows) {
            float vp = accP[rt][nt][r] + vbp[nt]; vp = vp > 0.f ? vp : 0.f;
            float vn = accN[rt][nt][r] + vbn[nt]; vn = vn > 0.f ? vn : 0.f;
            hout[(size_t)row * 128 + col] = f2bf(vp - vn);
          }
        }
      }
    }
  }
}

// ---- mean pool: one wave per 8 consecutive nodes (batch sorted -> few flushes) ----
__global__ void k_pool(const uint32_t* __restrict__ h, const int* __restrict__ batch,
                       float* __restrict__ pooled, float* __restrict__ gcnt, int n) {
  int gid = blockIdx.x * blockDim.x + threadIdx.x;
  int w = gid >> 6, lane = gid & 63;
  int n0 = w * 8;
  if (n0 >= n) return;
  int curg = -1, c = 0;
  float a0 = 0.f, a1 = 0.f;
  for (int i = 0; i < 8; ++i) {
    int nd = n0 + i;
    if (nd >= n) break;
    int g = batch[nd];
    if (g != curg) {
      if (curg >= 0) {
        atomicAdd(&pooled[curg * 128 + 2 * lane], a0);
        atomicAdd(&pooled[curg * 128 + 2 * lane + 1], a1);
        if (lane == 0) atomicAdd(gcnt + curg, (float)c);
      }
      curg = g; a0 = a1 = 0.f; c = 0;
    }
    uint32_t pk = h[nd * 64 + lane];
    a0 += bflo(pk); a1 += bfhi(pk); ++c;
  }
  if (curg >= 0) {
    atomicAdd(&pooled[curg * 128 + 2 * lane], a0);
    atomicAdd(&pooled[curg * 128 + 2 * lane + 1], a1);
    if (lane == 0) atomicAdd(gcnt + curg, (float)c);
  }
}

// ---- LayerNorm over D=128, one wave per graph ----
__global__ void k_ln(const float* __restrict__ pooled, const float* __restrict__ gcnt,
                     const float* __restrict__ gamma, const float* __restrict__ beta,
                     float* __restrict__ out, int G) {
  int gid = blockIdx.x * blockDim.x + threadIdx.x;
  int g = gid >> 6, lane = gid & 63;
  if (g >= G) return;
  float2 s = ((const float2*)pooled)[g * 64 + lane];
  float cm = fmaxf(gcnt[g], 1.f);
  float v0 = s.x / cm, v1 = s.y / cm;
  float tsum = v0 + v1;
#pragma unroll
  for (int m = 1; m < 64; m <<= 1) tsum += __shfl_xor(tsum, m, 64);
  float mu = tsum * (1.f / 128.f);
  float d0 = v0 - mu, d1 = v1 - mu;
  float q = d0 * d0 + d1 * d1;
#pragma unroll
  for (int m = 1; m < 64; m <<= 1) q += __shfl_xor(q, m, 64);
  float inv = rsqrtf(q * (1.f / 128.f) + 1e-5f);
  int f = 2 * lane;
  out[g * 128 + f]     = d0 * inv * gamma[f]     + beta[f];
  out[g * 128 + f + 1] = d1 * inv * gamma[f + 1] + beta[f + 1];
}

extern "C" void kernel_launch(void* const* d_in, const int* in_sizes, int n_in,
                              void* d_out, int out_size, void* d_ws, size_t ws_size,
                              hipStream_t stream) {
  const float* x     = (const float*)d_in[0];
  const int* ei      = (const int*)d_in[1];   // harness converts int64 -> int32
  const float* ew    = (const float*)d_in[2];
  const int* bt      = (const int*)d_in[3];   // int32
  const float* Wp    = (const float*)d_in[4];
  const float* bp    = (const float*)d_in[5];
  const float* Wn    = (const float*)d_in[6];
  const float* bn    = (const float*)d_in[7];
  const float* gamma = (const float*)d_in[8];
  const float* beta  = (const float*)d_in[9];
  int N = in_sizes[0] / 128;
  int E = in_sizes[1] / 2;
  int L = in_sizes[4] / (128 * 128);
  int G = out_size / 128;

  char* w = (char*)d_ws;
  auto alloc = [&](size_t bytes) {
    char* p = w;
    w += (bytes + 255) & ~(size_t)255;
    return p;
  };
  uint32_t* X   = (uint32_t*)alloc((size_t)N * 128 * 2);  // h (bf16 pairs)
  uint32_t* U   = (uint32_t*)alloc((size_t)N * 128 * 2);  // pos-branch agg
  uint32_t* V   = (uint32_t*)alloc((size_t)N * 128 * 2);  // neg-branch agg
  u16* wt       = (u16*)alloc((size_t)L * 2 * 128 * 128 * 2);
  int2* rec2    = (int2*)alloc((size_t)E * 8);
  int* cp       = (int*)alloc((size_t)N * 4);
  int* cn       = (int*)alloc((size_t)N * 4);
  int* offs     = (int*)alloc((size_t)(N + 1) * 4);
  int* cur      = (int*)alloc((size_t)N * 4);
  int* part     = (int*)alloc(1024 * 4);
  float* dp     = (float*)alloc((size_t)N * 4);
  float* dn     = (float*)alloc((size_t)N * 4);
  float* pooled = (float*)alloc((size_t)G * 128 * 4);
  float* gcnt   = (float*)alloc((size_t)G * 4);

  hipMemsetAsync(cp, 0, (size_t)N * 4, stream);
  hipMemsetAsync(cn, 0, (size_t)N * 4, stream);
  hipMemsetAsync(pooled, 0, (size_t)G * 128 * 4, stream);
  hipMemsetAsync(gcnt, 0, (size_t)G * 4, stream);

  int n4 = N * 32;
  k_cvt_x<<<(n4 + 255) / 256, 256, 0, stream>>>(x, X, n4);
  int wtot = L * 2 * 128 * 128;
  k_cvt_w<<<(wtot + 255) / 256, 256, 0, stream>>>(Wp, Wn, wt, wtot);
  k_count<<<(E + 255) / 256, 256, 0, stream>>>(ei, ew, cp, cn, E);
  int NB = (N + 1023) / 1024;
  k_scan1<<<NB, 1024, 0, stream>>>(cp, cn, offs, part, N);
  k_scan2<<<1, 64, 0, stream>>>(part, offs, NB, N);
  k_scan3<<<(N + 255) / 256, 256, 0, stream>>>(offs, part, cp, cn, cur, dp, dn, N);
  k_build<<<(E + 255) / 256, 256, 0, stream>>>(ei, ew, dp, dn, cur, rec2, E);

  int nchunks = (N + 127) / 128;
  for (int l = 0; l < L; ++l) {
    k_agg<<<(N * 64 + 255) / 256, 256, 0, stream>>>(X, offs, rec2, dp, dn, U, V, N);
    k_gemm<<<512, 256, 0, stream>>>((const short*)U, (const short*)V,
                                    wt + (size_t)l * 32768, bp + (size_t)l * 128,
                                    bn + (size_t)l * 128, (u16*)X, N, nchunks);
  }
  k_pool<<<(((N + 7) / 8) * 64 + 255) / 256, 256, 0, stream>>>(X, bt, pooled, gcnt, N);
  k_ln<<<(G * 64 + 255) / 256, 256, 0, stream>>>(pooled, gcnt, gamma, beta, (float*)d_out, G);
}